// Round 11
// baseline (1060.501 us; speedup 1.0000x reference)
//
#include <hip/hip_runtime.h>

#define N_NODES 50000
#define NPAD    50048   // 782 * 64, MFMA-tile padded
#define ZROW    50000   // dedicated all-zero row for clamped gather slots
#define N_EDGES 800000
#define EMB 128
#define NFEAT 9
#define VOCAB 119
#define NITER 10
#define ALPHA 0.1f
#define NCH 4           // dim chunks; 32 dims = 64B bf16 = 1 cache line per row

typedef __attribute__((ext_vector_type(8))) short bf16x8;
typedef __attribute__((ext_vector_type(4))) float f32x4;

// ---------------- bf16 helpers (manual RNE) ----------------

__device__ inline unsigned int f2bf1(float x) {
    union { float f; unsigned u; } v; v.f = x;
    unsigned r = v.u + 0x7fffu + ((v.u >> 16) & 1u);
    return r >> 16;
}
__device__ inline unsigned int f2bf2(float lo, float hi) {
    return f2bf1(lo) | (f2bf1(hi) << 16);
}
__device__ inline float bf2f_lo(unsigned u) {
    union { unsigned u; float f; } v; v.u = u << 16; return v.f;
}
__device__ inline float bf2f_hi(unsigned u) {
    union { unsigned u; float f; } v; v.u = u & 0xffff0000u; return v.f;
}

// ---------------- CSR build ----------------

__global__ void k_zero(int* __restrict__ cnt) {
    int i = blockIdx.x * blockDim.x + threadIdx.x;
    if (i < N_NODES) cnt[i] = 0;
}

__global__ void k_count(const int* __restrict__ dst, int* __restrict__ cnt,
                        int* __restrict__ ord) {
    int e = blockIdx.x * blockDim.x + threadIdx.x;
    if (e < N_EDGES) ord[e] = atomicAdd(&cnt[dst[e]], 1);
}

__global__ void k_scan1(const int* __restrict__ cnt, int* __restrict__ rowptr,
                        int* __restrict__ bsum, float* __restrict__ dinv) {
    __shared__ int s[256];
    int t = threadIdx.x;
    int idx = blockIdx.x * 256 + t;
    int v = (idx < N_NODES) ? cnt[idx] : 0;
    if (idx < N_NODES) dinv[idx] = rsqrtf((float)(v + 1));  // +1 self loop
    s[t] = v; __syncthreads();
    for (int off = 1; off < 256; off <<= 1) {
        int add = (t >= off) ? s[t - off] : 0;
        __syncthreads();
        s[t] += add;
        __syncthreads();
    }
    if (idx < N_NODES) rowptr[idx] = s[t] - v;   // exclusive
    if (t == 255) bsum[blockIdx.x] = s[255];     // block total
}

__global__ void k_scan2(int* __restrict__ bsum, int nb) {
    __shared__ int s[256];
    int t = threadIdx.x;
    int v = (t < nb) ? bsum[t] : 0;
    s[t] = v; __syncthreads();
    for (int off = 1; off < 256; off <<= 1) {
        int add = (t >= off) ? s[t - off] : 0;
        __syncthreads();
        s[t] += add;
        __syncthreads();
    }
    if (t < nb) bsum[t] = s[t] - v;              // exclusive block offsets
}

__global__ void k_scan3(int* __restrict__ rowptr, const int* __restrict__ bsum) {
    int idx = blockIdx.x * 256 + threadIdx.x;
    if (idx < N_NODES) rowptr[idx] += bsum[blockIdx.x];
}

// atomic-free fill; csr indices stored as ushort (ids < 65536)
__global__ void k_fill(const int* __restrict__ src, const int* __restrict__ dst,
                       const int* __restrict__ ord, const int* __restrict__ rowptr,
                       ushort* __restrict__ csr_u) {
    int e = blockIdx.x * blockDim.x + threadIdx.x;
    if (e < N_EDGES) {
        csr_u[rowptr[dst[e]] + ord[e]] = (ushort)src[e];
    }
}

// zero pad rows (incl. ZROW) of all chunks of both q buffers
__global__ void k_zpad(uint4* __restrict__ qA, uint4* __restrict__ qB) {
    int t = threadIdx.x;   // 1 block, 256 threads
    const uint4 z = make_uint4(0u, 0u, 0u, 0u);
    const int per_ch = (NPAD - N_NODES) * 4;   // 192 uint4 per chunk
    for (int i = t; i < NCH * per_ch; i += 256) {
        int ch = i / per_ch, r = i % per_ch;
        size_t idx = (size_t)ch * NPAD * 4 + (size_t)N_NODES * 4 + r;
        qA[idx] = z; qB[idx] = z;
    }
}

// ---------------- W prep: WT[l][n][k] = bf16(W[l][k][n]) ----------------

__global__ void k_wprep(const float* __restrict__ W, ushort* __restrict__ WT) {
    int l = blockIdx.x >> 7;        // layer 0..2
    int n = blockIdx.x & 127;
    int k = threadIdx.x;            // 128 threads
    WT[(l * 128 + n) * 128 + k] = (ushort)f2bf1(W[(l * 128 + k) * 128 + n]);
}

// ---------------- encoder -> bf16 ----------------

__global__ void k_encode(const int* __restrict__ x, const float* __restrict__ emb,
                         unsigned* __restrict__ hb) {
    int t = threadIdx.x;
    int sub = t >> 6;                   // node 0..3
    int dq = t & 63;                    // dim pair
    int n = blockIdx.x * 4 + sub;       // grid 12500 -> exact 50000
    const int* xr = x + n * NFEAT;
    float s0 = 0.f, s1 = 0.f;
#pragma unroll
    for (int f = 0; f < NFEAT; ++f) {
        const float2 e = *(const float2*)&emb[(f * VOCAB + xr[f]) * EMB + 2 * dq];
        s0 += e.x; s1 += e.y;
    }
    hb[n * 64 + dq] = f2bf2(s0, s1);
}

// ---------------- MLP via MFMA: 64 nodes/block, 4 waves ----------------

template <int RELU, int WQ>
__global__ __launch_bounds__(256) void k_mlp_mfma(
        const uint4* __restrict__ inb,     // bf16 [NPAD][128], row = 16 uint4
        uint4* __restrict__ outb,          // bf16 out (may == inb)
        const uint4* __restrict__ WT4,     // bf16 [128][128] n-major
        const float* __restrict__ bias,
        const float* __restrict__ dinv,
        float* __restrict__ h0out,         // WQ: f32 [NPAD][128]
        ushort* __restrict__ q0out,        // WQ: bf16 CHUNK-MAJOR [NCH][NPAD][32]
        ushort* __restrict__ h0bout) {     // WQ: bf16 [NPAD][128]
    int t = threadIdx.x;
    int w = t >> 6;
    int l = t & 63;
    int lr = l & 15;       // A-row / B-col / C-col within tile
    int kg = l >> 4;       // k-group 0..3
    int base = blockIdx.x * 64 + w * 16;
    union U { uint4 u; bf16x8 b; };

    int arow = base + lr;
    bf16x8 afrag[4];
#pragma unroll
    for (int kc = 0; kc < 4; ++kc) {
        U cu; cu.u = inb[arow * 16 + kc * 4 + kg];
        afrag[kc] = cu.b;
    }

    f32x4 acc[8];
#pragma unroll
    for (int nt = 0; nt < 8; ++nt) {
        float bv = bias[nt * 16 + lr];
        acc[nt] = (f32x4){bv, bv, bv, bv};
    }

#pragma unroll
    for (int kc = 0; kc < 4; ++kc) {
#pragma unroll
        for (int nt = 0; nt < 8; ++nt) {
            U cu; cu.u = WT4[(nt * 16 + lr) * 16 + kc * 4 + kg];
            acc[nt] = __builtin_amdgcn_mfma_f32_16x16x32_bf16(afrag[kc], cu.b,
                                                              acc[nt], 0, 0, 0);
        }
    }

    int orow = base + kg * 4;   // rows orow..orow+3 (reg index r)
    float dv[4];
    if (WQ) {
#pragma unroll
        for (int r = 0; r < 4; ++r) dv[r] = dinv[orow + r];
    }
#pragma unroll
    for (int nt = 0; nt < 8; ++nt) {
        int n = nt * 16 + lr;
#pragma unroll
        for (int r = 0; r < 4; ++r) {
            float val = acc[nt][r];
            if (RELU) val = fmaxf(val, 0.f);
            if (WQ) {
                h0out[(orow + r) * 128 + n] = val;
                // chunk-major q0: chunk = n>>5, within = n&31
                q0out[((size_t)(n >> 5) * NPAD + (orow + r)) * 32 + (n & 31)] =
                    (ushort)f2bf1(val * dv[r]);
                h0bout[(orow + r) * 128 + n] = (ushort)f2bf1(val);
            } else {
                ((ushort*)outb)[(orow + r) * 128 + n] = (ushort)f2bf1(val);
            }
        }
    }
}

// ---------------- propagation: dim-chunked, XCD-pinned ----------------
// q buffers are CHUNK-MAJOR bf16 [NCH][NPAD][32]; a chunk row = 64B = 1 line;
// per chunk = 3.2MB < 4MB per-XCD L2. chunk = (blockIdx&7)>>1 pins each chunk
// to one XCD pair (dispatch round-robins blocks across the 8 XCDs), so each
// XCD's L2 only caches its own chunk -> gathers become L2 hits.
// Wave per (node, chunk); lane = (slot 0..15, dq 0..3). One gather instr
// covers 16 edges (16 rows x 64B). Indices: per-lane ushort load (nt-hinted).

#define ACC8(g) \
    a0 += bf2f_lo((g).x); a1 += bf2f_hi((g).x); \
    a2 += bf2f_lo((g).y); a3 += bf2f_hi((g).y); \
    a4 += bf2f_lo((g).z); a5 += bf2f_hi((g).z); \
    a6 += bf2f_lo((g).w); a7 += bf2f_hi((g).w);

template <int LAST>
__global__ __launch_bounds__(256) void k_prop(const uint4* __restrict__ qin,
                                              const float4* __restrict__ h0f4,  // f32 (LAST)
                                              const uint4* __restrict__ h0b,    // bf16 node-major
                                              void* __restrict__ outb,
                                              const int* __restrict__ rowptr,
                                              const int* __restrict__ cnt,
                                              const ushort* __restrict__ csr_u,
                                              const float* __restrict__ dinv) {
    int t = threadIdx.x;
    int lane = t & 63;
    int slot = lane >> 2;              // edge slot 0..15
    int dq = lane & 3;                 // dims 8dq..8dq+7 within chunk
    int bid = blockIdx.x;
    int x = bid & 7;                   // XCD hint
    int ch = x >> 1;                   // chunk 0..3 pinned to XCD pair
    int j = bid >> 3;                  // 0..6249
    int v = ((j << 1) + (x & 1)) * 4 + (t >> 6);   // exact cover of 50000 nodes

    const uint4* qc = qin + (size_t)ch * NPAD * 4; // chunk base (uint4 units)
    int start = __builtin_amdgcn_readfirstlane(rowptr[v]);
    int c = __builtin_amdgcn_readfirstlane(cnt[v]);
    const ushort* cs = csr_u + start;
    float dv = dinv[v];
    uint4 qv = qc[v * 4 + dq];         // self row chunk (broadcast across slots)

    float a0 = 0.f, a1 = 0.f, a2 = 0.f, a3 = 0.f;
    float a4 = 0.f, a5 = 0.f, a6 = 0.f, a7 = 0.f;

    for (int i = 0; i < c; i += 16) {
        // per-lane index load (nt: don't evict the resident chunk)
        int sidx = (int)__builtin_nontemporal_load(cs + i + slot);
        int s = (i + slot < c) ? sidx : ZROW;
        uint4 g = qc[s * 4 + dq];      // 16 rows x 64B per instruction
        ACC8(g);
    }

    // reduce across 16 slots (lane bits 2..5)
    a0 += __shfl_xor(a0, 4); a0 += __shfl_xor(a0, 8); a0 += __shfl_xor(a0, 16); a0 += __shfl_xor(a0, 32);
    a1 += __shfl_xor(a1, 4); a1 += __shfl_xor(a1, 8); a1 += __shfl_xor(a1, 16); a1 += __shfl_xor(a1, 32);
    a2 += __shfl_xor(a2, 4); a2 += __shfl_xor(a2, 8); a2 += __shfl_xor(a2, 16); a2 += __shfl_xor(a2, 32);
    a3 += __shfl_xor(a3, 4); a3 += __shfl_xor(a3, 8); a3 += __shfl_xor(a3, 16); a3 += __shfl_xor(a3, 32);
    a4 += __shfl_xor(a4, 4); a4 += __shfl_xor(a4, 8); a4 += __shfl_xor(a4, 16); a4 += __shfl_xor(a4, 32);
    a5 += __shfl_xor(a5, 4); a5 += __shfl_xor(a5, 8); a5 += __shfl_xor(a5, 16); a5 += __shfl_xor(a5, 32);
    a6 += __shfl_xor(a6, 4); a6 += __shfl_xor(a6, 8); a6 += __shfl_xor(a6, 16); a6 += __shfl_xor(a6, 32);
    a7 += __shfl_xor(a7, 4); a7 += __shfl_xor(a7, 8); a7 += __shfl_xor(a7, 16); a7 += __shfl_xor(a7, 32);

    const float K = 1.f - ALPHA;

    if (LAST) {
        if (slot < 2) {
            float4 h0v = h0f4[v * 32 + ch * 8 + dq * 2 + slot];
            float b0, b1, b2, b3;
            if (slot == 0) {
                b0 = a0 + bf2f_lo(qv.x); b1 = a1 + bf2f_hi(qv.x);
                b2 = a2 + bf2f_lo(qv.y); b3 = a3 + bf2f_hi(qv.y);
            } else {
                b0 = a4 + bf2f_lo(qv.z); b1 = a5 + bf2f_hi(qv.z);
                b2 = a6 + bf2f_lo(qv.w); b3 = a7 + bf2f_hi(qv.w);
            }
            float4 res;
            res.x = K * dv * b0 + ALPHA * h0v.x;
            res.y = K * dv * b1 + ALPHA * h0v.y;
            res.z = K * dv * b2 + ALPHA * h0v.z;
            res.w = K * dv * b3 + ALPHA * h0v.w;
            ((float4*)outb)[v * 32 + ch * 8 + dq * 2 + slot] = res;
        }
    } else {
        if (slot == 0) {
            uint4 hvb = h0b[v * 16 + ch * 4 + dq];
            float s0 = a0 + bf2f_lo(qv.x), s1 = a1 + bf2f_hi(qv.x);
            float s2 = a2 + bf2f_lo(qv.y), s3 = a3 + bf2f_hi(qv.y);
            float s4 = a4 + bf2f_lo(qv.z), s5 = a5 + bf2f_hi(qv.z);
            float s6 = a6 + bf2f_lo(qv.w), s7 = a7 + bf2f_hi(qv.w);
            float h_0 = K * dv * s0 + ALPHA * bf2f_lo(hvb.x);
            float h_1 = K * dv * s1 + ALPHA * bf2f_hi(hvb.x);
            float h_2 = K * dv * s2 + ALPHA * bf2f_lo(hvb.y);
            float h_3 = K * dv * s3 + ALPHA * bf2f_hi(hvb.y);
            float h_4 = K * dv * s4 + ALPHA * bf2f_lo(hvb.z);
            float h_5 = K * dv * s5 + ALPHA * bf2f_hi(hvb.z);
            float h_6 = K * dv * s6 + ALPHA * bf2f_lo(hvb.w);
            float h_7 = K * dv * s7 + ALPHA * bf2f_hi(hvb.w);
            uint4 wv;
            wv.x = f2bf2(h_0 * dv, h_1 * dv);
            wv.y = f2bf2(h_2 * dv, h_3 * dv);
            wv.z = f2bf2(h_4 * dv, h_5 * dv);
            wv.w = f2bf2(h_6 * dv, h_7 * dv);
            ((uint4*)outb)[(size_t)ch * NPAD * 4 + v * 4 + dq] = wv;
        }
    }
}

// ---------------- host ----------------

extern "C" void kernel_launch(void* const* d_in, const int* in_sizes, int n_in,
                              void* d_out, int out_size, void* d_ws, size_t ws_size,
                              hipStream_t stream) {
    const int*   x    = (const int*)d_in[0];             // [N, 9]
    const int*   ei   = (const int*)d_in[1];             // [2, E]
    const float* emb  = (const float*)d_in[2];           // [9, 119, 128]
    const float* Ws   = (const float*)d_in[3];           // [3, 128, 128]
    const float* bs   = (const float*)d_in[4];           // [3, 128]
    float* out = (float*)d_out;                          // [N, 128] f32

    const int* src = ei;
    const int* dst = ei + N_EDGES;

    // workspace carve-up (byte-based, 256B-aligned chunks)
    char* w = (char*)d_ws;
    size_t off = 0;
    auto alloc = [&](size_t bytes) {
        void* p = w + off;
        off += (bytes + 255) & ~(size_t)255;
        return p;
    };
    float*  h0      = (float*)alloc((size_t)NPAD * EMB * 4);
    void*   hb      = alloc((size_t)NPAD * EMB * 2);   // bf16 MLP chain (in-place)
    void*   qA      = alloc((size_t)NCH * NPAD * 32 * 2);  // bf16 chunk-major
    void*   qB      = alloc((size_t)NCH * NPAD * 32 * 2);  // bf16 chunk-major
    void*   h0b     = alloc((size_t)NPAD * EMB * 2);   // bf16 copy of h0 (node-major)
    ushort* WT      = (ushort*)alloc((size_t)3 * 128 * 128 * 2);
    float*  dinv    = (float*)alloc((size_t)NPAD * 4);
    int*    cnt     = (int*)alloc(N_NODES * 4);
    int*    rowptr  = (int*)alloc(N_NODES * 4);
    int*    bsum    = (int*)alloc(256 * 4);
    ushort* csr_u   = (ushort*)alloc((N_EDGES + 64) * 2); // +pad for over-read
    int*    ord     = (int*)alloc(N_EDGES * 4);
    (void)ws_size; (void)n_in; (void)in_sizes; (void)out_size;

    const int NB_N  = (N_NODES + 255) / 256;   // 196
    const int NB_E  = (N_EDGES + 255) / 256;   // 3125
    const int NB_EN = N_NODES / 4;             // 12500 (encode, exact)
    const int NB_M  = NPAD / 64;               // 782 (mfma mlp)
    const int NB_P  = N_NODES;                 // 50000: (node x chunk) / 4-waves

    // CSR build
    k_zero<<<NB_N, 256, 0, stream>>>(cnt);
    k_count<<<NB_E, 256, 0, stream>>>(dst, cnt, ord);
    k_scan1<<<NB_N, 256, 0, stream>>>(cnt, rowptr, bsum, dinv);
    k_scan2<<<1, 256, 0, stream>>>(bsum, NB_N);
    k_scan3<<<NB_N, 256, 0, stream>>>(rowptr, bsum);
    k_fill<<<NB_E, 256, 0, stream>>>(src, dst, ord, rowptr, csr_u);

    // W transpose->bf16, encoder->bf16, 3 MFMA MLP layers (in-place on hb)
    k_wprep<<<384, 128, 0, stream>>>(Ws, WT);
    k_encode<<<NB_EN, 256, 0, stream>>>(x, emb, (unsigned*)hb);
    k_mlp_mfma<1, 0><<<NB_M, 256, 0, stream>>>(
        (const uint4*)hb, (uint4*)hb, (const uint4*)(WT + 0 * 128 * 128),
        bs + 0 * EMB, nullptr, nullptr, nullptr, nullptr);
    k_mlp_mfma<1, 0><<<NB_M, 256, 0, stream>>>(
        (const uint4*)hb, (uint4*)hb, (const uint4*)(WT + 1 * 128 * 128),
        bs + 1 * EMB, nullptr, nullptr, nullptr, nullptr);
    k_mlp_mfma<0, 1><<<NB_M, 256, 0, stream>>>(
        (const uint4*)hb, nullptr, (const uint4*)(WT + 2 * 128 * 128),
        bs + 2 * EMB, dinv, h0, (ushort*)qA, (ushort*)h0b);

    // zero pad rows (incl. ZROW) of every chunk AFTER the MLP wrote garbage there
    k_zpad<<<1, 256, 0, stream>>>((uint4*)qA, (uint4*)qB);

    // 10 propagation iterations on chunk-major bf16 q; last writes f32 h to d_out
    const uint4* qin = (const uint4*)qA;
    for (int i = 0; i < NITER; ++i) {
        if (i == NITER - 1) {
            k_prop<1><<<NB_P, 256, 0, stream>>>(qin, (const float4*)h0,
                                                (const uint4*)h0b, out,
                                                rowptr, cnt, csr_u, dinv);
        } else {
            void* qo = (i & 1) ? qA : qB;
            k_prop<0><<<NB_P, 256, 0, stream>>>(qin, (const float4*)h0,
                                                (const uint4*)h0b, qo,
                                                rowptr, cnt, csr_u, dinv);
            qin = (const uint4*)qo;
        }
    }
}

// Round 12
// 862.124 us; speedup vs baseline: 1.2301x; 1.2301x over previous
//
#include <hip/hip_runtime.h>

#define N_NODES 50000
#define NPAD    50048   // 782 * 64, MFMA-tile padded
#define ZROW    50000   // dedicated all-zero row for padded CSR slots
#define N_EDGES 800000
#define CSRCAP  1000000 // padded CSR capacity: E + 3N + slack
#define EMB 128
#define NFEAT 9
#define VOCAB 119
#define NITER 10
#define ALPHA 0.1f
#define NCH 4           // dim chunks; 32 dims = 64B bf16 = 1 cache line per row

typedef __attribute__((ext_vector_type(8))) short bf16x8;
typedef __attribute__((ext_vector_type(4))) float f32x4;

// ---------------- bf16 helpers (manual RNE) ----------------

__device__ inline unsigned int f2bf1(float x) {
    union { float f; unsigned u; } v; v.f = x;
    unsigned r = v.u + 0x7fffu + ((v.u >> 16) & 1u);
    return r >> 16;
}
__device__ inline unsigned int f2bf2(float lo, float hi) {
    return f2bf1(lo) | (f2bf1(hi) << 16);
}
__device__ inline float bf2f_lo(unsigned u) {
    union { unsigned u; float f; } v; v.u = u << 16; return v.f;
}
__device__ inline float bf2f_hi(unsigned u) {
    union { unsigned u; float f; } v; v.u = u & 0xffff0000u; return v.f;
}

// unaligned-friendly int4 (CSR groups start at 16B-unaligned dword offsets)
struct __attribute__((aligned(4))) i4 { int x, y, z, w; };

// ---------------- CSR build (padded to 4-edge groups with ZROW) ----------------

__global__ void k_zero(int* __restrict__ cnt) {
    int i = blockIdx.x * blockDim.x + threadIdx.x;
    if (i < N_NODES) cnt[i] = 0;
}

// prefill padded CSR with ZROW so pad slots gather zeros
__global__ void k_csrz(int* __restrict__ csr) {
    int i = blockIdx.x * blockDim.x + threadIdx.x;
    if (i < CSRCAP) csr[i] = ZROW;
}

__global__ void k_count(const int* __restrict__ dst, int* __restrict__ cnt,
                        int* __restrict__ ord) {
    int e = blockIdx.x * blockDim.x + threadIdx.x;
    if (e < N_EDGES) ord[e] = atomicAdd(&cnt[dst[e]], 1);
}

// scan PADDED counts ((c+3)&~3) -> rowptr; dinv from real count
__global__ void k_scan1(const int* __restrict__ cnt, int* __restrict__ rowptr,
                        int* __restrict__ bsum, float* __restrict__ dinv) {
    __shared__ int s[256];
    int t = threadIdx.x;
    int idx = blockIdx.x * 256 + t;
    int v = (idx < N_NODES) ? cnt[idx] : 0;
    if (idx < N_NODES) dinv[idx] = rsqrtf((float)(v + 1));  // +1 self loop
    int v4 = (v + 3) & ~3;
    s[t] = v4; __syncthreads();
    for (int off = 1; off < 256; off <<= 1) {
        int add = (t >= off) ? s[t - off] : 0;
        __syncthreads();
        s[t] += add;
        __syncthreads();
    }
    if (idx < N_NODES) rowptr[idx] = s[t] - v4;  // exclusive over padded counts
    if (t == 255) bsum[blockIdx.x] = s[255];     // block total
}

__global__ void k_scan2(int* __restrict__ bsum, int nb) {
    __shared__ int s[256];
    int t = threadIdx.x;
    int v = (t < nb) ? bsum[t] : 0;
    s[t] = v; __syncthreads();
    for (int off = 1; off < 256; off <<= 1) {
        int add = (t >= off) ? s[t - off] : 0;
        __syncthreads();
        s[t] += add;
        __syncthreads();
    }
    if (t < nb) bsum[t] = s[t] - v;              // exclusive block offsets
}

__global__ void k_scan3(int* __restrict__ rowptr, const int* __restrict__ bsum) {
    int idx = blockIdx.x * 256 + threadIdx.x;
    if (idx < N_NODES) rowptr[idx] += bsum[blockIdx.x];
}

// atomic-free fill into the ZROW-prefilled padded CSR
__global__ void k_fill(const int* __restrict__ src, const int* __restrict__ dst,
                       const int* __restrict__ ord, const int* __restrict__ rowptr,
                       int* __restrict__ csr) {
    int e = blockIdx.x * blockDim.x + threadIdx.x;
    if (e < N_EDGES) {
        csr[rowptr[dst[e]] + ord[e]] = src[e];
    }
}

// zero pad rows (incl. ZROW) of all chunks of both q buffers
__global__ void k_zpad(uint4* __restrict__ qA, uint4* __restrict__ qB) {
    int t = threadIdx.x;   // 1 block, 256 threads
    const uint4 z = make_uint4(0u, 0u, 0u, 0u);
    const int per_ch = (NPAD - N_NODES) * 4;   // 192 uint4 per chunk
    for (int i = t; i < NCH * per_ch; i += 256) {
        int ch = i / per_ch, r = i % per_ch;
        size_t idx = (size_t)ch * NPAD * 4 + (size_t)N_NODES * 4 + r;
        qA[idx] = z; qB[idx] = z;
    }
}

// ---------------- W prep: WT[l][n][k] = bf16(W[l][k][n]) ----------------

__global__ void k_wprep(const float* __restrict__ W, ushort* __restrict__ WT) {
    int l = blockIdx.x >> 7;        // layer 0..2
    int n = blockIdx.x & 127;
    int k = threadIdx.x;            // 128 threads
    WT[(l * 128 + n) * 128 + k] = (ushort)f2bf1(W[(l * 128 + k) * 128 + n]);
}

// ---------------- encoder -> bf16 ----------------

__global__ void k_encode(const int* __restrict__ x, const float* __restrict__ emb,
                         unsigned* __restrict__ hb) {
    int t = threadIdx.x;
    int sub = t >> 6;                   // node 0..3
    int dq = t & 63;                    // dim pair
    int n = blockIdx.x * 4 + sub;       // grid 12500 -> exact 50000
    const int* xr = x + n * NFEAT;
    float s0 = 0.f, s1 = 0.f;
#pragma unroll
    for (int f = 0; f < NFEAT; ++f) {
        const float2 e = *(const float2*)&emb[(f * VOCAB + xr[f]) * EMB + 2 * dq];
        s0 += e.x; s1 += e.y;
    }
    hb[n * 64 + dq] = f2bf2(s0, s1);
}

// ---------------- MLP via MFMA: 64 nodes/block, 4 waves ----------------

template <int RELU, int WQ>
__global__ __launch_bounds__(256) void k_mlp_mfma(
        const uint4* __restrict__ inb,     // bf16 [NPAD][128], row = 16 uint4
        uint4* __restrict__ outb,          // bf16 out (may == inb)
        const uint4* __restrict__ WT4,     // bf16 [128][128] n-major
        const float* __restrict__ bias,
        const float* __restrict__ dinv,
        float* __restrict__ h0out,         // WQ: f32 [NPAD][128]
        ushort* __restrict__ q0out,        // WQ: bf16 CHUNK-MAJOR [NCH][NPAD][32]
        ushort* __restrict__ h0bout) {     // WQ: bf16 [NPAD][128]
    int t = threadIdx.x;
    int w = t >> 6;
    int l = t & 63;
    int lr = l & 15;       // A-row / B-col / C-col within tile
    int kg = l >> 4;       // k-group 0..3
    int base = blockIdx.x * 64 + w * 16;
    union U { uint4 u; bf16x8 b; };

    int arow = base + lr;
    bf16x8 afrag[4];
#pragma unroll
    for (int kc = 0; kc < 4; ++kc) {
        U cu; cu.u = inb[arow * 16 + kc * 4 + kg];
        afrag[kc] = cu.b;
    }

    f32x4 acc[8];
#pragma unroll
    for (int nt = 0; nt < 8; ++nt) {
        float bv = bias[nt * 16 + lr];
        acc[nt] = (f32x4){bv, bv, bv, bv};
    }

#pragma unroll
    for (int kc = 0; kc < 4; ++kc) {
#pragma unroll
        for (int nt = 0; nt < 8; ++nt) {
            U cu; cu.u = WT4[(nt * 16 + lr) * 16 + kc * 4 + kg];
            acc[nt] = __builtin_amdgcn_mfma_f32_16x16x32_bf16(afrag[kc], cu.b,
                                                              acc[nt], 0, 0, 0);
        }
    }

    int orow = base + kg * 4;   // rows orow..orow+3 (reg index r)
    float dv[4];
    if (WQ) {
#pragma unroll
        for (int r = 0; r < 4; ++r) dv[r] = dinv[orow + r];
    }
#pragma unroll
    for (int nt = 0; nt < 8; ++nt) {
        int n = nt * 16 + lr;
#pragma unroll
        for (int r = 0; r < 4; ++r) {
            float val = acc[nt][r];
            if (RELU) val = fmaxf(val, 0.f);
            if (WQ) {
                h0out[(orow + r) * 128 + n] = val;
                // chunk-major q0: chunk = n>>5, within = n&31
                q0out[((size_t)(n >> 5) * NPAD + (orow + r)) * 32 + (n & 31)] =
                    (ushort)f2bf1(val * dv[r]);
                h0bout[(orow + r) * 128 + n] = (ushort)f2bf1(val);
            } else {
                ((ushort*)outb)[(orow + r) * 128 + n] = (ushort)f2bf1(val);
            }
        }
    }
}

// ---------------- propagation: dim-chunked, XCD-pinned, low-overhead ----------------
// q chunk-major bf16 [NCH][NPAD][32]: row = 64B; chunk = 3.2MB < 4MB per-XCD L2.
// chunk = (blockIdx&7)>>1 pins chunks to XCD pairs via dispatch round-robin.
// Lane = (slot 0..3, dq 0..15): u32 load (2 dims); 16 dq-lanes = one 64B row;
// 4 slots = 4 edges/instr; 16-edge group = 4 gathers in flight (round-10 ILP).
// CSR is ZROW-padded to 4-multiples -> no clamp logic. Reduce = 2 accs x 2 shfl.

#define SEL(iv) (slot == 0 ? (iv).x : slot == 1 ? (iv).y : slot == 2 ? (iv).z : (iv).w)

template <int LAST>
__global__ __launch_bounds__(256) void k_prop(const unsigned* __restrict__ qin,
                                              const float2* __restrict__ h0f2,  // f32 (LAST)
                                              const unsigned* __restrict__ h0b, // bf16 node-major
                                              void* __restrict__ outb,
                                              const int* __restrict__ rowptr,
                                              const int* __restrict__ cnt,
                                              const int* __restrict__ csr,
                                              const float* __restrict__ dinv) {
    int t = threadIdx.x;
    int lane = t & 63;
    int slot = lane >> 4;              // edge sub-slot 0..3
    int dq = lane & 15;                // u32 (dim pair) within 64B chunk row
    int bid = blockIdx.x;
    int x = bid & 7;                   // XCD hint
    int ch = x >> 1;                   // chunk 0..3 pinned to XCD pair
    int j = bid >> 3;                  // 0..6249
    int v = ((j << 1) + (x & 1)) * 4 + (t >> 6);   // exact cover of 50000 nodes

    const unsigned* qc = qin + (size_t)ch * NPAD * 16;  // chunk base (u32 units)
    int start = __builtin_amdgcn_readfirstlane(rowptr[v]);
    int c = __builtin_amdgcn_readfirstlane(cnt[v]);
    int c4 = (c + 3) & ~3;             // padded edge count (ZROW-filled)
    const int* cs = csr + start;
    float dv = dinv[v];
    unsigned qv = qc[v * 16 + dq];     // self row chunk (uniform over slots)

    float a0 = 0.f, a1 = 0.f;
    int i = 0;
    for (; i + 16 <= c4; i += 16) {
        i4 ia = *(const i4*)(cs + i);
        i4 ib = *(const i4*)(cs + i + 4);
        i4 ic = *(const i4*)(cs + i + 8);
        i4 id = *(const i4*)(cs + i + 12);
        int s0 = SEL(ia), s1 = SEL(ib), s2 = SEL(ic), s3 = SEL(id);
        unsigned g0 = qc[s0 * 16 + dq];
        unsigned g1 = qc[s1 * 16 + dq];
        unsigned g2 = qc[s2 * 16 + dq];
        unsigned g3 = qc[s3 * 16 + dq];
        a0 += bf2f_lo(g0) + bf2f_lo(g1);
        a1 += bf2f_hi(g0) + bf2f_hi(g1);
        a0 += bf2f_lo(g2) + bf2f_lo(g3);
        a1 += bf2f_hi(g2) + bf2f_hi(g3);
    }
    for (; i < c4; i += 4) {
        i4 ia = *(const i4*)(cs + i);
        int s0 = SEL(ia);
        unsigned g0 = qc[s0 * 16 + dq];
        a0 += bf2f_lo(g0);
        a1 += bf2f_hi(g0);
    }

    // reduce across 4 slots (lane bits 4,5)
    a0 += __shfl_xor(a0, 16); a0 += __shfl_xor(a0, 32);
    a1 += __shfl_xor(a1, 16); a1 += __shfl_xor(a1, 32);

    const float K = 1.f - ALPHA;
    if (slot == 0) {
        float b0 = a0 + bf2f_lo(qv);
        float b1 = a1 + bf2f_hi(qv);
        if (LAST) {
            float2 h0v = h0f2[v * 64 + ch * 16 + dq];
            float2 res;
            res.x = K * dv * b0 + ALPHA * h0v.x;
            res.y = K * dv * b1 + ALPHA * h0v.y;
            ((float2*)outb)[v * 64 + ch * 16 + dq] = res;
        } else {
            unsigned hvb = h0b[v * 64 + ch * 16 + dq];
            float h_0 = K * dv * b0 + ALPHA * bf2f_lo(hvb);
            float h_1 = K * dv * b1 + ALPHA * bf2f_hi(hvb);
            ((unsigned*)outb)[(size_t)ch * NPAD * 16 + v * 16 + dq] =
                f2bf2(h_0 * dv, h_1 * dv);
        }
    }
}

// ---------------- host ----------------

extern "C" void kernel_launch(void* const* d_in, const int* in_sizes, int n_in,
                              void* d_out, int out_size, void* d_ws, size_t ws_size,
                              hipStream_t stream) {
    const int*   x    = (const int*)d_in[0];             // [N, 9]
    const int*   ei   = (const int*)d_in[1];             // [2, E]
    const float* emb  = (const float*)d_in[2];           // [9, 119, 128]
    const float* Ws   = (const float*)d_in[3];           // [3, 128, 128]
    const float* bs   = (const float*)d_in[4];           // [3, 128]
    float* out = (float*)d_out;                          // [N, 128] f32

    const int* src = ei;
    const int* dst = ei + N_EDGES;

    // workspace carve-up (byte-based, 256B-aligned chunks)
    char* w = (char*)d_ws;
    size_t off = 0;
    auto alloc = [&](size_t bytes) {
        void* p = w + off;
        off += (bytes + 255) & ~(size_t)255;
        return p;
    };
    float*  h0      = (float*)alloc((size_t)NPAD * EMB * 4);
    void*   hb      = alloc((size_t)NPAD * EMB * 2);       // bf16 MLP chain (in-place)
    void*   qA      = alloc((size_t)NCH * NPAD * 32 * 2);  // bf16 chunk-major
    void*   qB      = alloc((size_t)NCH * NPAD * 32 * 2);  // bf16 chunk-major
    void*   h0b     = alloc((size_t)NPAD * EMB * 2);       // bf16 h0, node-major
    ushort* WT      = (ushort*)alloc((size_t)3 * 128 * 128 * 2);
    float*  dinv    = (float*)alloc((size_t)NPAD * 4);
    int*    cnt     = (int*)alloc(N_NODES * 4);
    int*    rowptr  = (int*)alloc(N_NODES * 4);
    int*    bsum    = (int*)alloc(256 * 4);
    int*    csr     = (int*)alloc((size_t)CSRCAP * 4);     // ZROW-prefilled, padded
    int*    ord     = (int*)alloc(N_EDGES * 4);
    (void)ws_size; (void)n_in; (void)in_sizes; (void)out_size;

    const int NB_N  = (N_NODES + 255) / 256;   // 196
    const int NB_E  = (N_EDGES + 255) / 256;   // 3125
    const int NB_C  = (CSRCAP + 255) / 256;    // 3907
    const int NB_EN = N_NODES / 4;             // 12500 (encode, exact)
    const int NB_M  = NPAD / 64;               // 782 (mfma mlp)
    const int NB_P  = N_NODES;                 // 50000: (node x chunk) blocks

    // CSR build (padded, atomic-free fill)
    k_zero<<<NB_N, 256, 0, stream>>>(cnt);
    k_csrz<<<NB_C, 256, 0, stream>>>(csr);
    k_count<<<NB_E, 256, 0, stream>>>(dst, cnt, ord);
    k_scan1<<<NB_N, 256, 0, stream>>>(cnt, rowptr, bsum, dinv);
    k_scan2<<<1, 256, 0, stream>>>(bsum, NB_N);
    k_scan3<<<NB_N, 256, 0, stream>>>(rowptr, bsum);
    k_fill<<<NB_E, 256, 0, stream>>>(src, dst, ord, rowptr, csr);

    // W transpose->bf16, encoder->bf16, 3 MFMA MLP layers (in-place on hb)
    k_wprep<<<384, 128, 0, stream>>>(Ws, WT);
    k_encode<<<NB_EN, 256, 0, stream>>>(x, emb, (unsigned*)hb);
    k_mlp_mfma<1, 0><<<NB_M, 256, 0, stream>>>(
        (const uint4*)hb, (uint4*)hb, (const uint4*)(WT + 0 * 128 * 128),
        bs + 0 * EMB, nullptr, nullptr, nullptr, nullptr);
    k_mlp_mfma<1, 0><<<NB_M, 256, 0, stream>>>(
        (const uint4*)hb, (uint4*)hb, (const uint4*)(WT + 1 * 128 * 128),
        bs + 1 * EMB, nullptr, nullptr, nullptr, nullptr);
    k_mlp_mfma<0, 1><<<NB_M, 256, 0, stream>>>(
        (const uint4*)hb, nullptr, (const uint4*)(WT + 2 * 128 * 128),
        bs + 2 * EMB, dinv, h0, (ushort*)qA, (ushort*)h0b);

    // zero pad rows (incl. ZROW) of every chunk AFTER the MLP wrote there
    k_zpad<<<1, 256, 0, stream>>>((uint4*)qA, (uint4*)qB);

    // 10 propagation iterations on chunk-major bf16 q; last writes f32 h to d_out
    const unsigned* qin = (const unsigned*)qA;
    for (int i = 0; i < NITER; ++i) {
        if (i == NITER - 1) {
            k_prop<1><<<NB_P, 256, 0, stream>>>(qin, (const float2*)h0,
                                                (const unsigned*)h0b, out,
                                                rowptr, cnt, csr, dinv);
        } else {
            void* qo = (i & 1) ? qA : qB;
            k_prop<0><<<NB_P, 256, 0, stream>>>(qin, (const float2*)h0,
                                                (const unsigned*)h0b, qo,
                                                rowptr, cnt, csr, dinv);
            qin = (const unsigned*)qo;
        }
    }
}

// Round 14
// 538.324 us; speedup vs baseline: 1.9700x; 1.6015x over previous
//
#include <hip/hip_runtime.h>

#define N_NODES 50000
#define NPAD    50048   // 782 * 64, MFMA-tile padded
#define ZROW    50000   // dedicated all-zero row for clamped gather slots
#define N_EDGES 800000
#define EMB 128
#define NFEAT 9
#define VOCAB 119
#define NITER 10
#define ALPHA 0.1f

typedef __attribute__((ext_vector_type(8))) short bf16x8;
typedef __attribute__((ext_vector_type(4))) float f32x4;

// ---------------- bf16 helpers (manual RNE) ----------------

__device__ inline unsigned int f2bf1(float x) {
    union { float f; unsigned u; } v; v.f = x;
    unsigned r = v.u + 0x7fffu + ((v.u >> 16) & 1u);
    return r >> 16;
}
__device__ inline unsigned int f2bf2(float lo, float hi) {
    return f2bf1(lo) | (f2bf1(hi) << 16);
}
__device__ inline float bf2f_lo(unsigned u) {
    union { unsigned u; float f; } v; v.u = u << 16; return v.f;
}
__device__ inline float bf2f_hi(unsigned u) {
    union { unsigned u; float f; } v; v.u = u & 0xffff0000u; return v.f;
}

// unaligned-friendly int4 (CSR rows start at arbitrary dword offsets)
struct __attribute__((aligned(4))) i4 { int x, y, z, w; };

// ---------------- CSR build ----------------

__global__ void k_zero(int* __restrict__ cnt) {
    int i = blockIdx.x * blockDim.x + threadIdx.x;
    if (i < N_NODES) cnt[i] = 0;
}

__global__ void k_count(const int* __restrict__ dst, int* __restrict__ cnt,
                        int* __restrict__ ord) {
    int e = blockIdx.x * blockDim.x + threadIdx.x;
    if (e < N_EDGES) ord[e] = atomicAdd(&cnt[dst[e]], 1);
}

__global__ void k_scan1(const int* __restrict__ cnt, int* __restrict__ rowptr,
                        int* __restrict__ bsum, float* __restrict__ dinv) {
    __shared__ int s[256];
    int t = threadIdx.x;
    int idx = blockIdx.x * 256 + t;
    int v = (idx < N_NODES) ? cnt[idx] : 0;
    if (idx < N_NODES) dinv[idx] = rsqrtf((float)(v + 1));  // +1 self loop
    s[t] = v; __syncthreads();
    for (int off = 1; off < 256; off <<= 1) {
        int add = (t >= off) ? s[t - off] : 0;
        __syncthreads();
        s[t] += add;
        __syncthreads();
    }
    if (idx < N_NODES) rowptr[idx] = s[t] - v;   // exclusive
    if (t == 255) bsum[blockIdx.x] = s[255];     // block total
}

__global__ void k_scan2(int* __restrict__ bsum, int nb) {
    __shared__ int s[256];
    int t = threadIdx.x;
    int v = (t < nb) ? bsum[t] : 0;
    s[t] = v; __syncthreads();
    for (int off = 1; off < 256; off <<= 1) {
        int add = (t >= off) ? s[t - off] : 0;
        __syncthreads();
        s[t] += add;
        __syncthreads();
    }
    if (t < nb) bsum[t] = s[t] - v;              // exclusive block offsets
}

__global__ void k_scan3(int* __restrict__ rowptr, const int* __restrict__ bsum) {
    int idx = blockIdx.x * 256 + threadIdx.x;
    if (idx < N_NODES) rowptr[idx] += bsum[blockIdx.x];
}

__global__ void k_fill(const int* __restrict__ src, const int* __restrict__ dst,
                       const int* __restrict__ ord, const int* __restrict__ rowptr,
                       int* __restrict__ csr_src) {
    int e = blockIdx.x * blockDim.x + threadIdx.x;
    if (e < N_EDGES) {
        csr_src[rowptr[dst[e]] + ord[e]] = src[e];
    }
}

// zero the pad rows (incl. ZROW) of both q buffers: 48 rows * 16 uint4 * 2
__global__ void k_zpad(uint4* __restrict__ qA, uint4* __restrict__ qB) {
    int t = threadIdx.x;   // 256 threads, 1 block
    const uint4 z = make_uint4(0u, 0u, 0u, 0u);
    for (int i = t; i < (NPAD - N_NODES) * 16; i += 256) {
        qA[(size_t)N_NODES * 16 + i] = z;
        qB[(size_t)N_NODES * 16 + i] = z;
    }
}

// ---------------- W prep: WT[l][n][k] = bf16(W[l][k][n]) ----------------

__global__ void k_wprep(const float* __restrict__ W, ushort* __restrict__ WT) {
    int l = blockIdx.x >> 7;        // layer 0..2
    int n = blockIdx.x & 127;
    int k = threadIdx.x;            // 128 threads
    WT[(l * 128 + n) * 128 + k] = (ushort)f2bf1(W[(l * 128 + k) * 128 + n]);
}

// ---------------- encoder -> bf16 ----------------

__global__ void k_encode(const int* __restrict__ x, const float* __restrict__ emb,
                         unsigned* __restrict__ hb) {
    int t = threadIdx.x;
    int sub = t >> 6;                   // node 0..3
    int dq = t & 63;                    // dim pair
    int n = blockIdx.x * 4 + sub;       // grid 12500 -> exact 50000
    const int* xr = x + n * NFEAT;
    float s0 = 0.f, s1 = 0.f;
#pragma unroll
    for (int f = 0; f < NFEAT; ++f) {
        const float2 e = *(const float2*)&emb[(f * VOCAB + xr[f]) * EMB + 2 * dq];
        s0 += e.x; s1 += e.y;
    }
    hb[n * 64 + dq] = f2bf2(s0, s1);
}

// ---------------- MLP via MFMA: 64 nodes/block, 4 waves ----------------

template <int RELU, int WQ>
__global__ __launch_bounds__(256) void k_mlp_mfma(
        const uint4* __restrict__ inb,     // bf16 [NPAD][128], row = 16 uint4
        uint4* __restrict__ outb,          // bf16 out (may == inb; per-block in-place safe)
        const uint4* __restrict__ WT4,     // bf16 [128][128] n-major
        const float* __restrict__ bias,
        const float* __restrict__ dinv,
        float* __restrict__ h0out,         // WQ: f32
        ushort* __restrict__ q0out,        // WQ: bf16 dinv*h
        ushort* __restrict__ h0bout) {     // WQ: bf16 h
    int t = threadIdx.x;
    int w = t >> 6;
    int l = t & 63;
    int lr = l & 15;       // A-row / B-col / C-col within tile
    int kg = l >> 4;       // k-group 0..3
    int base = blockIdx.x * 64 + w * 16;
    union U { uint4 u; bf16x8 b; };

    int arow = base + lr;
    bf16x8 afrag[4];
#pragma unroll
    for (int kc = 0; kc < 4; ++kc) {
        U cu; cu.u = inb[arow * 16 + kc * 4 + kg];
        afrag[kc] = cu.b;
    }

    f32x4 acc[8];
#pragma unroll
    for (int nt = 0; nt < 8; ++nt) {
        float bv = bias[nt * 16 + lr];
        acc[nt] = (f32x4){bv, bv, bv, bv};
    }

#pragma unroll
    for (int kc = 0; kc < 4; ++kc) {
#pragma unroll
        for (int nt = 0; nt < 8; ++nt) {
            U cu; cu.u = WT4[(nt * 16 + lr) * 16 + kc * 4 + kg];
            acc[nt] = __builtin_amdgcn_mfma_f32_16x16x32_bf16(afrag[kc], cu.b,
                                                              acc[nt], 0, 0, 0);
        }
    }

    int orow = base + kg * 4;   // rows orow..orow+3 (reg index r)
    float dv[4];
    if (WQ) {
#pragma unroll
        for (int r = 0; r < 4; ++r) dv[r] = dinv[orow + r];
    }
#pragma unroll
    for (int nt = 0; nt < 8; ++nt) {
        int n = nt * 16 + lr;
#pragma unroll
        for (int r = 0; r < 4; ++r) {
            float val = acc[nt][r];
            if (RELU) val = fmaxf(val, 0.f);
            if (WQ) {
                h0out[(orow + r) * 128 + n] = val;
                q0out[(orow + r) * 128 + n] = (ushort)f2bf1(val * dv[r]);
                h0bout[(orow + r) * 128 + n] = (ushort)f2bf1(val);
            } else {
                ((ushort*)outb)[(orow + r) * 128 + n] = (ushort)f2bf1(val);
            }
        }
    }
}

// ---------------- propagation on bf16 q = dinv*h ----------------
// Tiered static fast paths: deg<=16 -> 4 gathers issued up-front; deg<=32 -> 8;
// else loop. Empty slots clamp to ZROW (a zeroed pad row), so no masking cost.

#define ACC8(g) \
    a0 += bf2f_lo((g).x); a1 += bf2f_hi((g).x); \
    a2 += bf2f_lo((g).y); a3 += bf2f_hi((g).y); \
    a4 += bf2f_lo((g).z); a5 += bf2f_hi((g).z); \
    a6 += bf2f_lo((g).w); a7 += bf2f_hi((g).w);

#define SEL(iv) (pair == 0 ? (iv).x : pair == 1 ? (iv).y : pair == 2 ? (iv).z : (iv).w)

template <int LAST>
__global__ __launch_bounds__(256) void k_prop(const uint4* __restrict__ qin,
                                              const float4* __restrict__ h0,   // f32 (LAST)
                                              const uint4* __restrict__ h0b,   // bf16
                                              void* __restrict__ outb,
                                              const int* __restrict__ rowptr,
                                              const int* __restrict__ cnt,
                                              const int* __restrict__ csr_src,
                                              const float* __restrict__ dinv) {
    int t = threadIdx.x;
    int lane = t & 63;
    int pair = lane >> 4;              // 0..3: edge sub-slot
    int dq = lane & 15;                // dims 8dq..8dq+7
    int v = blockIdx.x * 4 + (t >> 6); // 12500 * 4 == 50000 exactly
    int start = __builtin_amdgcn_readfirstlane(rowptr[v]);
    int c = __builtin_amdgcn_readfirstlane(cnt[v]);
    const int* cs = csr_src + start;

    // hoisted self/anchor loads overlap the edge gathers
    float dv = dinv[v];
    uint4 qv = qin[v * 16 + dq];
    float4 hlo, hhi; uint4 hvb;
    if (LAST) {
        hlo = h0[v * 32 + 2 * dq];
        hhi = h0[v * 32 + 2 * dq + 1];
    } else {
        hvb = h0b[v * 16 + dq];
    }

    float a0 = 0.f, a1 = 0.f, a2 = 0.f, a3 = 0.f;
    float a4 = 0.f, a5 = 0.f, a6 = 0.f, a7 = 0.f;

    if (c <= 16) {
        // csr_src padded +32 ints -> over-read is safe; empty slots -> ZROW
        i4 ia = *(const i4*)(cs + 0);
        i4 ib = *(const i4*)(cs + 4);
        i4 ic = *(const i4*)(cs + 8);
        i4 id = *(const i4*)(cs + 12);
        int s0 = (0  + pair < c) ? SEL(ia) : ZROW;
        int s1 = (4  + pair < c) ? SEL(ib) : ZROW;
        int s2 = (8  + pair < c) ? SEL(ic) : ZROW;
        int s3 = (12 + pair < c) ? SEL(id) : ZROW;
        uint4 g0 = qin[s0 * 16 + dq];
        uint4 g1 = qin[s1 * 16 + dq];
        uint4 g2 = qin[s2 * 16 + dq];
        uint4 g3 = qin[s3 * 16 + dq];
        ACC8(g0); ACC8(g1); ACC8(g2); ACC8(g3);
    } else if (c <= 32) {
        i4 ia = *(const i4*)(cs + 0);
        i4 ib = *(const i4*)(cs + 4);
        i4 ic = *(const i4*)(cs + 8);
        i4 id = *(const i4*)(cs + 12);
        i4 ie = *(const i4*)(cs + 16);
        i4 ifq = *(const i4*)(cs + 20);
        i4 ig = *(const i4*)(cs + 24);
        i4 ih = *(const i4*)(cs + 28);
        int s0 = (0  + pair < c) ? SEL(ia) : ZROW;
        int s1 = (4  + pair < c) ? SEL(ib) : ZROW;
        int s2 = (8  + pair < c) ? SEL(ic) : ZROW;
        int s3 = (12 + pair < c) ? SEL(id) : ZROW;
        int s4 = (16 + pair < c) ? SEL(ie) : ZROW;
        int s5 = (20 + pair < c) ? SEL(ifq) : ZROW;
        int s6 = (24 + pair < c) ? SEL(ig) : ZROW;
        int s7 = (28 + pair < c) ? SEL(ih) : ZROW;
        uint4 g0 = qin[s0 * 16 + dq];
        uint4 g1 = qin[s1 * 16 + dq];
        uint4 g2 = qin[s2 * 16 + dq];
        uint4 g3 = qin[s3 * 16 + dq];
        uint4 g4 = qin[s4 * 16 + dq];
        uint4 g5 = qin[s5 * 16 + dq];
        uint4 g6 = qin[s6 * 16 + dq];
        uint4 g7 = qin[s7 * 16 + dq];
        ACC8(g0); ACC8(g1); ACC8(g2); ACC8(g3);
        ACC8(g4); ACC8(g5); ACC8(g6); ACC8(g7);
    } else {
        int i = 0;
        for (; i + 32 <= c; i += 32) {
            i4 ia = *(const i4*)(cs + i);
            i4 ib = *(const i4*)(cs + i + 4);
            i4 ic = *(const i4*)(cs + i + 8);
            i4 id = *(const i4*)(cs + i + 12);
            i4 ie = *(const i4*)(cs + i + 16);
            i4 ifq = *(const i4*)(cs + i + 20);
            i4 ig = *(const i4*)(cs + i + 24);
            i4 ih = *(const i4*)(cs + i + 28);
            int s0 = SEL(ia), s1 = SEL(ib), s2 = SEL(ic), s3 = SEL(id);
            int s4 = SEL(ie), s5 = SEL(ifq), s6 = SEL(ig), s7 = SEL(ih);
            uint4 g0 = qin[s0 * 16 + dq];
            uint4 g1 = qin[s1 * 16 + dq];
            uint4 g2 = qin[s2 * 16 + dq];
            uint4 g3 = qin[s3 * 16 + dq];
            uint4 g4 = qin[s4 * 16 + dq];
            uint4 g5 = qin[s5 * 16 + dq];
            uint4 g6 = qin[s6 * 16 + dq];
            uint4 g7 = qin[s7 * 16 + dq];
            ACC8(g0); ACC8(g1); ACC8(g2); ACC8(g3);
            ACC8(g4); ACC8(g5); ACC8(g6); ACC8(g7);
        }
        // masked tail: up to 32 edges via ZROW clamp
        if (i < c) {
            i4 ia = *(const i4*)(cs + i);
            i4 ib = *(const i4*)(cs + i + 4);
            i4 ic = *(const i4*)(cs + i + 8);
            i4 id = *(const i4*)(cs + i + 12);
            i4 ie = *(const i4*)(cs + i + 16);
            i4 ifq = *(const i4*)(cs + i + 20);
            i4 ig = *(const i4*)(cs + i + 24);
            i4 ih = *(const i4*)(cs + i + 28);
            int s0 = (i + 0  + pair < c) ? SEL(ia) : ZROW;
            int s1 = (i + 4  + pair < c) ? SEL(ib) : ZROW;
            int s2 = (i + 8  + pair < c) ? SEL(ic) : ZROW;
            int s3 = (i + 12 + pair < c) ? SEL(id) : ZROW;
            int s4 = (i + 16 + pair < c) ? SEL(ie) : ZROW;
            int s5 = (i + 20 + pair < c) ? SEL(ifq) : ZROW;
            int s6 = (i + 24 + pair < c) ? SEL(ig) : ZROW;
            int s7 = (i + 28 + pair < c) ? SEL(ih) : ZROW;
            uint4 g0 = qin[s0 * 16 + dq];
            uint4 g1 = qin[s1 * 16 + dq];
            uint4 g2 = qin[s2 * 16 + dq];
            uint4 g3 = qin[s3 * 16 + dq];
            uint4 g4 = qin[s4 * 16 + dq];
            uint4 g5 = qin[s5 * 16 + dq];
            uint4 g6 = qin[s6 * 16 + dq];
            uint4 g7 = qin[s7 * 16 + dq];
            ACC8(g0); ACC8(g1); ACC8(g2); ACC8(g3);
            ACC8(g4); ACC8(g5); ACC8(g6); ACC8(g7);
        }
    }

    a0 += __shfl_xor(a0, 16); a0 += __shfl_xor(a0, 32);
    a1 += __shfl_xor(a1, 16); a1 += __shfl_xor(a1, 32);
    a2 += __shfl_xor(a2, 16); a2 += __shfl_xor(a2, 32);
    a3 += __shfl_xor(a3, 16); a3 += __shfl_xor(a3, 32);
    a4 += __shfl_xor(a4, 16); a4 += __shfl_xor(a4, 32);
    a5 += __shfl_xor(a5, 16); a5 += __shfl_xor(a5, 32);
    a6 += __shfl_xor(a6, 16); a6 += __shfl_xor(a6, 32);
    a7 += __shfl_xor(a7, 16); a7 += __shfl_xor(a7, 32);

    float s0 = a0 + bf2f_lo(qv.x), s1 = a1 + bf2f_hi(qv.x);
    float s2 = a2 + bf2f_lo(qv.y), s3 = a3 + bf2f_hi(qv.y);
    float s4 = a4 + bf2f_lo(qv.z), s5 = a5 + bf2f_hi(qv.z);
    float s6 = a6 + bf2f_lo(qv.w), s7 = a7 + bf2f_hi(qv.w);
    const float K = 1.f - ALPHA;

    if (LAST) {
        float h_0 = K * dv * s0 + ALPHA * hlo.x;
        float h_1 = K * dv * s1 + ALPHA * hlo.y;
        float h_2 = K * dv * s2 + ALPHA * hlo.z;
        float h_3 = K * dv * s3 + ALPHA * hlo.w;
        float h_4 = K * dv * s4 + ALPHA * hhi.x;
        float h_5 = K * dv * s5 + ALPHA * hhi.y;
        float h_6 = K * dv * s6 + ALPHA * hhi.z;
        float h_7 = K * dv * s7 + ALPHA * hhi.w;
        if (pair < 2) {
            float4 wv = (pair == 0) ? make_float4(h_0, h_1, h_2, h_3)
                                    : make_float4(h_4, h_5, h_6, h_7);
            ((float4*)outb)[v * 32 + 2 * dq + pair] = wv;
        }
    } else {
        float h_0 = K * dv * s0 + ALPHA * bf2f_lo(hvb.x);
        float h_1 = K * dv * s1 + ALPHA * bf2f_hi(hvb.x);
        float h_2 = K * dv * s2 + ALPHA * bf2f_lo(hvb.y);
        float h_3 = K * dv * s3 + ALPHA * bf2f_hi(hvb.y);
        float h_4 = K * dv * s4 + ALPHA * bf2f_lo(hvb.z);
        float h_5 = K * dv * s5 + ALPHA * bf2f_hi(hvb.z);
        float h_6 = K * dv * s6 + ALPHA * bf2f_lo(hvb.w);
        float h_7 = K * dv * s7 + ALPHA * bf2f_hi(hvb.w);
        if (pair == 0) {
            uint4 wv;
            wv.x = f2bf2(h_0 * dv, h_1 * dv);
            wv.y = f2bf2(h_2 * dv, h_3 * dv);
            wv.z = f2bf2(h_4 * dv, h_5 * dv);
            wv.w = f2bf2(h_6 * dv, h_7 * dv);
            ((uint4*)outb)[v * 16 + dq] = wv;
        }
    }
}

// ---------------- host ----------------

extern "C" void kernel_launch(void* const* d_in, const int* in_sizes, int n_in,
                              void* d_out, int out_size, void* d_ws, size_t ws_size,
                              hipStream_t stream) {
    const int*   x    = (const int*)d_in[0];             // [N, 9]
    const int*   ei   = (const int*)d_in[1];             // [2, E]
    const float* emb  = (const float*)d_in[2];           // [9, 119, 128]
    const float* Ws   = (const float*)d_in[3];           // [3, 128, 128]
    const float* bs   = (const float*)d_in[4];           // [3, 128]
    float* out = (float*)d_out;                          // [N, 128] f32

    const int* src = ei;
    const int* dst = ei + N_EDGES;

    // workspace carve-up (byte-based, 256B-aligned chunks); node buffers padded to NPAD
    char* w = (char*)d_ws;
    size_t off = 0;
    auto alloc = [&](size_t bytes) {
        void* p = w + off;
        off += (bytes + 255) & ~(size_t)255;
        return p;
    };
    float*  h0      = (float*)alloc((size_t)NPAD * EMB * 4);
    void*   hb      = alloc((size_t)NPAD * EMB * 2);   // bf16 MLP chain (in-place)
    void*   qA      = alloc((size_t)NPAD * EMB * 2);   // bf16
    void*   qB      = alloc((size_t)NPAD * EMB * 2);   // bf16
    void*   h0b     = alloc((size_t)NPAD * EMB * 2);   // bf16 copy of h0
    ushort* WT      = (ushort*)alloc((size_t)3 * 128 * 128 * 2);
    float*  dinv    = (float*)alloc((size_t)NPAD * 4);
    int*    cnt     = (int*)alloc(N_NODES * 4);
    int*    rowptr  = (int*)alloc(N_NODES * 4);
    int*    bsum    = (int*)alloc(256 * 4);
    int*    csr_src = (int*)alloc((N_EDGES + 32) * 4);  // +32 pad for fast-path over-read
    int*    ord     = (int*)alloc(N_EDGES * 4);
    (void)ws_size; (void)n_in; (void)in_sizes; (void)out_size;

    const int NB_N  = (N_NODES + 255) / 256;   // 196
    const int NB_E  = (N_EDGES + 255) / 256;   // 3125
    const int NB_EN = N_NODES / 4;             // 12500 (encode, exact)
    const int NB_M  = NPAD / 64;               // 782 (mfma mlp)
    const int NB_P  = N_NODES / 4;             // 12500 (prop, exact)

    // CSR build
    k_zero<<<NB_N, 256, 0, stream>>>(cnt);
    k_count<<<NB_E, 256, 0, stream>>>(dst, cnt, ord);
    k_scan1<<<NB_N, 256, 0, stream>>>(cnt, rowptr, bsum, dinv);
    k_scan2<<<1, 256, 0, stream>>>(bsum, NB_N);
    k_scan3<<<NB_N, 256, 0, stream>>>(rowptr, bsum);
    k_fill<<<NB_E, 256, 0, stream>>>(src, dst, ord, rowptr, csr_src);

    // W transpose->bf16, encoder->bf16, 3 MFMA MLP layers (in-place on hb)
    k_wprep<<<384, 128, 0, stream>>>(Ws, WT);
    k_encode<<<NB_EN, 256, 0, stream>>>(x, emb, (unsigned*)hb);
    k_mlp_mfma<1, 0><<<NB_M, 256, 0, stream>>>(
        (const uint4*)hb, (uint4*)hb, (const uint4*)(WT + 0 * 128 * 128),
        bs + 0 * EMB, nullptr, nullptr, nullptr, nullptr);
    k_mlp_mfma<1, 0><<<NB_M, 256, 0, stream>>>(
        (const uint4*)hb, (uint4*)hb, (const uint4*)(WT + 1 * 128 * 128),
        bs + 1 * EMB, nullptr, nullptr, nullptr, nullptr);
    k_mlp_mfma<0, 1><<<NB_M, 256, 0, stream>>>(
        (const uint4*)hb, nullptr, (const uint4*)(WT + 2 * 128 * 128),
        bs + 2 * EMB, dinv, h0, (ushort*)qA, (ushort*)h0b);

    // zero pad rows (incl. ZROW) AFTER the MLP wrote garbage there
    k_zpad<<<1, 256, 0, stream>>>((uint4*)qA, (uint4*)qB);

    // 10 propagation iterations on bf16 q; last writes f32 h to d_out
    const uint4* qin = (const uint4*)qA;
    for (int i = 0; i < NITER; ++i) {
        if (i == NITER - 1) {
            k_prop<1><<<NB_P, 256, 0, stream>>>(qin, (const float4*)h0,
                                                (const uint4*)h0b, out,
                                                rowptr, cnt, csr_src, dinv);
        } else {
            void* qo = (i & 1) ? qA : qB;
            k_prop<0><<<NB_P, 256, 0, stream>>>(qin, (const float4*)h0,
                                                (const uint4*)h0b, qo,
                                                rowptr, cnt, csr_src, dinv);
            qin = (const uint4*)qo;
        }
    }
}